// Round 10
// baseline (139.292 us; speedup 1.0000x reference)
//
#include <hip/hip_runtime.h>
#include <hip/hip_bf16.h>

// TokenEncoder: B=8 L=2048 D=512 DM=1024 S=32 M=4 P=4096
// out = [tokens (8,2049,1024) f32][attn_keep (8,2049) as f32]

#define NB   8
#define NL   2048
#define ND   512
#define NDM  1024
#define NS   32
#define NTOK (NB * NL)          // 16384
#define LP1  (NL + 1)           // 2049
#define MAXTILES 160
#define EXP_CAP 1024

static __device__ __forceinline__ size_t attn_off() { return (size_t)NB * LP1 * NDM; }

typedef __attribute__((ext_vector_type(8))) short bf16x8;
typedef __attribute__((ext_vector_type(4))) float f32x4;

__device__ __forceinline__ unsigned short f2bf(float f) {
    unsigned int x = __float_as_uint(f);
    x += 0x7fffu + ((x >> 16) & 1u);   // RNE (inputs finite)
    return (unsigned short)(x >> 16);
}

__device__ __forceinline__ float bf2f(unsigned short s) {
    return __uint_as_float(((unsigned int)s) << 16);
}

// native conversion: compiler emits v_cvt_pk_bf16_f32 (RNE)
__device__ __forceinline__ bf16x8 cvt8(float4 a, float4 b) {
    bf16x8 r;
    r[0] = (short)__bfloat16_as_ushort(__float2bfloat16(a.x));
    r[1] = (short)__bfloat16_as_ushort(__float2bfloat16(a.y));
    r[2] = (short)__bfloat16_as_ushort(__float2bfloat16(a.z));
    r[3] = (short)__bfloat16_as_ushort(__float2bfloat16(a.w));
    r[4] = (short)__bfloat16_as_ushort(__float2bfloat16(b.x));
    r[5] = (short)__bfloat16_as_ushort(__float2bfloat16(b.y));
    r[6] = (short)__bfloat16_as_ushort(__float2bfloat16(b.z));
    r[7] = (short)__bfloat16_as_ushort(__float2bfloat16(b.w));
    return r;
}

__device__ __forceinline__ float4 ld4(const float* p) { return *(const float4*)p; }
__device__ __forceinline__ float4 add4(float4 a, float4 b) {
    return make_float4(a.x + b.x, a.y + b.y, a.z + b.z, a.w + b.w);
}

// ---- kernel 1: bucket tokens per expert; kidx per token; attn mask ----
__global__ void k_bucket(const int* __restrict__ sid, const int* __restrict__ mask,
                         int* __restrict__ cnt, int* __restrict__ kidx,
                         int* __restrict__ tokList, float* __restrict__ out) {
    int t = blockIdx.x * 256 + threadIdx.x;
    if (t >= NTOK) return;
    int s = sid[t];
    bool keep = mask[t] != 0;
    int b = t >> 11, l = t & (NL - 1);
    out[attn_off() + (size_t)b * LP1 + l + 1] = keep ? 1.0f : 0.0f;
    if (t < NB) out[attn_off() + (size_t)t * LP1] = 1.0f;   // CLS keep
    int ki = -1;
    if (keep) {
        ki = atomicAdd(&cnt[s], 1);
        if (ki < EXP_CAP) tokList[s * EXP_CAP + ki] = t;
    }
    kidx[t] = ki;
}

// ---- kernel 2: tile descriptors + compact prefix offsets + mod*role table ----
__global__ void k_tiles(const int* __restrict__ cnt, int* __restrict__ meta,
                        int* __restrict__ bOff, int4* __restrict__ tiles,
                        const float* __restrict__ me, const float* __restrict__ re,
                        float* __restrict__ mrT) {
    if (threadIdx.x == 0) {
        int idx = 0, cbase = 0;
        for (int e = 0; e < NS; ++e) {
            int c = min(cnt[e], EXP_CAP);
            bOff[e] = cbase;
            for (int r = 0; r < c; r += 128)
                tiles[idx++] = make_int4(e, r, min(128, c - r), cbase + r);
            cbase += c;
        }
        meta[0] = idx;
    }
    for (int i = threadIdx.x; i < 12 * (NDM / 4); i += 256) {
        int mr = i / (NDM / 4); int o = (i % (NDM / 4)) * 4;
        int m = mr / 3, ro = mr % 3;
        float4 v = add4(ld4(me + (size_t)m * NDM + o), ld4(re + (size_t)ro * NDM + o));
        *(float4*)&mrT[(size_t)mr * NDM + o] = v;
    }
}

// ---- kernel 3: grouped GEMM, f32 sources, fused in-reg cvt, reg-staged ----
__global__ __launch_bounds__(256, 4) void k_gemm(
    const float* __restrict__ emb, const float* __restrict__ Wp,
    const int* __restrict__ tokList, const int4* __restrict__ tiles,
    const int* __restrict__ meta, unsigned short* __restrict__ projC) {
    if (blockIdx.x >= meta[0]) return;
    int4 td = tiles[blockIdx.x];
    const int e = td.x, rowBase = td.y, nRows = td.z, cBase = td.w;
    const int nBase = blockIdx.y * 128;

    __shared__ short SA[128 * 32];   // 8 KB, single buffer
    __shared__ short SB[128 * 32];   // 8 KB

    const int tid  = threadIdx.x;
    const int lane = tid & 63;
    const int w    = tid >> 6;
    const int wr   = w >> 1, wc = w & 1;    // 2x2 waves, 64x64 out each
    const int fr   = lane & 15, kg = lane >> 4;

    // staging (r8-proven geometry): thread covers rows (srow, srow+64), 8-elem
    // chunk sch; loads are f32 (2x float4 per row-chunk), converted in-reg,
    // ds_write carries the XOR swizzle chunk^((row>>1)&3); ds_read same.
    const int srow = tid >> 2;              // 0..63
    const int sch  = tid & 3;
    const size_t eBase = (size_t)e * EXP_CAP + rowBase;
    int ar0 = (srow < nRows) ? srow : 0;
    int ar1 = (srow + 64 < nRows) ? srow + 64 : 0;
    int tok0 = tokList[eBase + ar0];
    int tok1 = tokList[eBase + ar1];
    const float* a0 = emb + (size_t)tok0 * ND + sch * 8;
    const float* a1 = emb + (size_t)tok1 * ND + sch * 8;
    const float* b0 = Wp + ((size_t)e * NDM + nBase + srow) * ND + sch * 8;
    const float* b1 = Wp + ((size_t)e * NDM + nBase + srow + 64) * ND + sch * 8;
    const int wo0 = srow * 32 + (sch ^ ((srow >> 1) & 3)) * 8;
    const int wo1 = wo0 + 64 * 32;

    f32x4 acc[4][4];
#pragma unroll
    for (int i = 0; i < 4; ++i)
#pragma unroll
        for (int j = 0; j < 4; ++j)
            acc[i][j] = (f32x4){0.f, 0.f, 0.f, 0.f};

    float4 ra0a = ld4(a0), ra0b = ld4(a0 + 4);
    float4 ra1a = ld4(a1), ra1b = ld4(a1 + 4);
    float4 rb0a = ld4(b0), rb0b = ld4(b0 + 4);
    float4 rb1a = ld4(b1), rb1b = ld4(b1 + 4);

    const int pc = kg ^ ((fr >> 1) & 3);    // swizzled physical chunk (lane-const)
    for (int ks = 0; ks < ND / 32; ++ks) {  // 16 K-steps
        __syncthreads();
        *(bf16x8*)&SA[wo0] = cvt8(ra0a, ra0b);
        *(bf16x8*)&SA[wo1] = cvt8(ra1a, ra1b);
        *(bf16x8*)&SB[wo0] = cvt8(rb0a, rb0b);
        *(bf16x8*)&SB[wo1] = cvt8(rb1a, rb1b);
        __syncthreads();
        if (ks < ND / 32 - 1) {             // next-step loads retire under MFMA
            const float* na0 = a0 + (ks + 1) * 32;
            const float* na1 = a1 + (ks + 1) * 32;
            const float* nb0 = b0 + (ks + 1) * 32;
            const float* nb1 = b1 + (ks + 1) * 32;
            ra0a = ld4(na0); ra0b = ld4(na0 + 4);
            ra1a = ld4(na1); ra1b = ld4(na1 + 4);
            rb0a = ld4(nb0); rb0b = ld4(nb0 + 4);
            rb1a = ld4(nb1); rb1b = ld4(nb1 + 4);
        }
        bf16x8 af[4], bv[4];
#pragma unroll
        for (int i = 0; i < 4; ++i)
            af[i] = *(const bf16x8*)&SA[(wr * 64 + i * 16 + fr) * 32 + pc * 8];
#pragma unroll
        for (int j = 0; j < 4; ++j)
            bv[j] = *(const bf16x8*)&SB[(wc * 64 + j * 16 + fr) * 32 + pc * 8];
#pragma unroll
        for (int i = 0; i < 4; ++i)
#pragma unroll
            for (int j = 0; j < 4; ++j)
                acc[i][j] = __builtin_amdgcn_mfma_f32_16x16x32_bf16(af[i], bv[j], acc[i][j], 0, 0, 0);
    }

    // epilogue: compact bf16 write, page-local (128 rows x 256KB window)
#pragma unroll
    for (int i = 0; i < 4; ++i) {
#pragma unroll
        for (int r = 0; r < 4; ++r) {
            int row = wr * 64 + i * 16 + kg * 4 + r;
            if (row < nRows) {
                size_t crow = (size_t)(cBase + row) * NDM + nBase;
#pragma unroll
                for (int j = 0; j < 4; ++j)
                    projC[crow + wc * 64 + j * 16 + fr] = f2bf(acc[i][j][r]);
            }
        }
    }
}

// ---- kernel 4: ALL output rows, row-contiguous 4KB writes ----
__global__ void k_out(const int* __restrict__ pos, const int* __restrict__ sid,
                      const int* __restrict__ mod, const int* __restrict__ role,
                      const int* __restrict__ mask, const int* __restrict__ kidx,
                      const int* __restrict__ bOff,
                      const float* __restrict__ bp, const float* __restrict__ cls_c,
                      const float* __restrict__ pe, const float* __restrict__ ie,
                      const float* __restrict__ mrT,
                      const unsigned short* __restrict__ projC,
                      float* __restrict__ out) {
    int l1 = blockIdx.x;            // 0..2048
    int b  = blockIdx.y;            // 0..7
    int o  = threadIdx.x * 4;       // 256 threads x 4 floats = 1024
    float4 v;
    if (l1 == 0) {
        v = add4(add4(ld4(cls_c + o), ld4(pe + o)), ld4(ie + (size_t)NS * NDM + o));
    } else {
        int t = b * NL + l1 - 1;
        int p = pos[t], s = sid[t], mr = mod[t] * 3 + role[t];
        v = add4(ld4(pe + (size_t)p * NDM + o), ld4(ie + (size_t)s * NDM + o));
        v = add4(v, ld4(mrT + (size_t)mr * NDM + o));
        if (mask[t] != 0) {
            v = add4(v, ld4(bp + (size_t)s * NDM + o));
            int ki = kidx[t];
            if (ki >= 0 && ki < EXP_CAP) {
                const unsigned short* pr = projC + (size_t)(bOff[s] + ki) * NDM + o;
                v.x += bf2f(pr[0]); v.y += bf2f(pr[1]);
                v.z += bf2f(pr[2]); v.w += bf2f(pr[3]);
            }
        }
    }
    *(float4*)&out[((size_t)b * LP1 + l1) * NDM + o] = v;
}

extern "C" void kernel_launch(void* const* d_in, const int* in_sizes, int n_in,
                              void* d_out, int out_size, void* d_ws, size_t ws_size,
                              hipStream_t stream) {
    const float* emb  = (const float*)d_in[0];
    const int* pos    = (const int*)d_in[1];
    const int* sid    = (const int*)d_in[2];
    const int* mod    = (const int*)d_in[3];
    const int* role   = (const int*)d_in[4];
    const int* mask   = (const int*)d_in[5];   // np.bool_ pushed as int32
    const float* Wp   = (const float*)d_in[6];
    const float* bp   = (const float*)d_in[7];
    const float* cls  = (const float*)d_in[8];
    const float* pe   = (const float*)d_in[9];
    const float* ie   = (const float*)d_in[10];
    const float* me   = (const float*)d_in[11];
    const float* re   = (const float*)d_in[12];
    float* out = (float*)d_out;

    int* ws        = (int*)d_ws;
    int* cnt       = ws;                          // [0..31]
    int* meta      = ws + 32;                     // [32]
    int* bOff      = ws + 64;                     // [64..95]
    int4* tiles    = (int4*)(ws + 128);           // 160 * int4
    int* tokList   = ws + 1024;                   // 32*1024
    int* kidx      = ws + 33792;                  // 16384
    float* mrT     = (float*)(ws + 50176);        // 12*1024
    unsigned short* projC = (unsigned short*)((char*)d_ws + 262144);  // 33.55 MB
    // total ws required: ~33.8 MB

    hipMemsetAsync(ws, 0, 64 * sizeof(int), stream);
    k_bucket<<<NTOK / 256, 256, 0, stream>>>(sid, mask, cnt, kidx, tokList, out);
    k_tiles<<<1, 256, 0, stream>>>(cnt, meta, bOff, tiles, me, re, mrT);

    dim3 gg(MAXTILES, NDM / 128);
    k_gemm<<<gg, 256, 0, stream>>>(emb, Wp, tokList, tiles, meta, projC);

    dim3 go(LP1, NB);
    k_out<<<go, 256, 0, stream>>>(pos, sid, mod, role, mask, kidx, bOff,
                                  bp, cls, pe, ie, mrT, projC, out);
}

// Round 11
// 129.290 us; speedup vs baseline: 1.0774x; 1.0774x over previous
//
#include <hip/hip_runtime.h>
#include <hip/hip_bf16.h>

// TokenEncoder: B=8 L=2048 D=512 DM=1024 S=32 M=4 P=4096
// out = [tokens (8,2049,1024) f32][attn_keep (8,2049) as f32]

#define NB   8
#define NL   2048
#define ND   512
#define NDM  1024
#define NS   32
#define NTOK (NB * NL)          // 16384
#define LP1  (NL + 1)           // 2049
#define MAXTILES 160
#define EXP_CAP 1024
#define EMB_ELEMS (NTOK * ND)   // 8388608
#define W_ELEMS (NS * NDM * ND) // 16777216

static __device__ __forceinline__ size_t attn_off() { return (size_t)NB * LP1 * NDM; }

typedef __attribute__((ext_vector_type(8))) short bf16x8;
typedef __attribute__((ext_vector_type(4))) float f32x4;

__device__ __forceinline__ unsigned short f2bf(float f) {
    unsigned int x = __float_as_uint(f);
    x += 0x7fffu + ((x >> 16) & 1u);   // RNE (inputs finite)
    return (unsigned short)(x >> 16);
}

__device__ __forceinline__ float bf2f(unsigned short s) {
    return __uint_as_float(((unsigned int)s) << 16);
}

// native conversion: compiler emits v_cvt_pk_bf16_f32 (RNE)
__device__ __forceinline__ bf16x8 cvt8(float4 a, float4 b) {
    bf16x8 r;
    r[0] = (short)__bfloat16_as_ushort(__float2bfloat16(a.x));
    r[1] = (short)__bfloat16_as_ushort(__float2bfloat16(a.y));
    r[2] = (short)__bfloat16_as_ushort(__float2bfloat16(a.z));
    r[3] = (short)__bfloat16_as_ushort(__float2bfloat16(a.w));
    r[4] = (short)__bfloat16_as_ushort(__float2bfloat16(b.x));
    r[5] = (short)__bfloat16_as_ushort(__float2bfloat16(b.y));
    r[6] = (short)__bfloat16_as_ushort(__float2bfloat16(b.z));
    r[7] = (short)__bfloat16_as_ushort(__float2bfloat16(b.w));
    return r;
}

__device__ __forceinline__ float4 ld4(const float* p) { return *(const float4*)p; }
__device__ __forceinline__ float4 add4(float4 a, float4 b) {
    return make_float4(a.x + b.x, a.y + b.y, a.z + b.z, a.w + b.w);
}

// ---- kernel 1: bucket tokens per expert; kidx per token; attn mask ----
__global__ void k_bucket(const int* __restrict__ sid, const int* __restrict__ mask,
                         int* __restrict__ cnt, int* __restrict__ kidx,
                         int* __restrict__ tokList, float* __restrict__ out) {
    int t = blockIdx.x * 256 + threadIdx.x;
    if (t >= NTOK) return;
    int s = sid[t];
    bool keep = mask[t] != 0;
    int b = t >> 11, l = t & (NL - 1);
    out[attn_off() + (size_t)b * LP1 + l + 1] = keep ? 1.0f : 0.0f;
    if (t < NB) out[attn_off() + (size_t)t * LP1] = 1.0f;   // CLS keep
    int ki = -1;
    if (keep) {
        ki = atomicAdd(&cnt[s], 1);
        if (ki < EXP_CAP) tokList[s * EXP_CAP + ki] = t;
    }
    kidx[t] = ki;
}

// ---- kernel 2: f32->bf16 stream (32 elems/thread) + tiles/bOff/mrT in block 0 ----
__global__ void k_cvt(const float* __restrict__ emb, const float* __restrict__ W,
                      short* __restrict__ embBf, short* __restrict__ wBf,
                      const int* __restrict__ cnt, int* __restrict__ meta,
                      int* __restrict__ bOff, int4* __restrict__ tiles,
                      const float* __restrict__ me, const float* __restrict__ re,
                      float* __restrict__ mrT) {
    if (blockIdx.x == 0) {
        if (threadIdx.x == 0) {         // tile descriptors + compact offsets
            int idx = 0, cbase = 0;
            for (int e = 0; e < NS; ++e) {
                int c = min(cnt[e], EXP_CAP);
                bOff[e] = cbase;
                for (int r = 0; r < c; r += 128)
                    tiles[idx++] = make_int4(e, r, min(128, c - r), cbase + r);
                cbase += c;
            }
            meta[0] = idx;
        }
        for (int i = threadIdx.x; i < 12 * (NDM / 4); i += 256) {   // mod*role table
            int mr = i / (NDM / 4); int o = (i % (NDM / 4)) * 4;
            int m = mr / 3, ro = mr % 3;
            float4 v = add4(ld4(me + (size_t)m * NDM + o), ld4(re + (size_t)ro * NDM + o));
            *(float4*)&mrT[(size_t)mr * NDM + o] = v;
        }
    }
    size_t i = ((size_t)blockIdx.x * 256 + threadIdx.x) * 32;
    const float* src; short* dst;
    if (i < (size_t)EMB_ELEMS) { src = emb + i; dst = embBf + i; }
    else { src = W + (i - EMB_ELEMS); dst = wBf + (i - EMB_ELEMS); }
    float4 v[8];
#pragma unroll
    for (int u = 0; u < 8; ++u) v[u] = ld4(src + u * 4);   // 4 independent 32B pairs
#pragma unroll
    for (int u = 0; u < 4; ++u)
        *(bf16x8*)(dst + u * 8) = cvt8(v[u * 2], v[u * 2 + 1]);
}

// ---- kernel 3: grouped GEMM (r9-proven): bf16 reg-staged, compact projC write ----
__global__ __launch_bounds__(256, 4) void k_gemm(
    const short* __restrict__ embBf, const short* __restrict__ wBf,
    const int* __restrict__ tokList, const int4* __restrict__ tiles,
    const int* __restrict__ meta, unsigned short* __restrict__ projC) {
    if (blockIdx.x >= meta[0]) return;
    int4 td = tiles[blockIdx.x];
    const int e = td.x, rowBase = td.y, nRows = td.z, cBase = td.w;
    const int nBase = blockIdx.y * 128;

    __shared__ short SA[128 * 32];   // 8 KB, single buffer
    __shared__ short SB[128 * 32];   // 8 KB

    const int tid  = threadIdx.x;
    const int lane = tid & 63;
    const int w    = tid >> 6;
    const int wr   = w >> 1, wc = w & 1;    // 2x2 waves, 64x64 out each
    const int fr   = lane & 15, kg = lane >> 4;

    // staging: thread covers rows (srow, srow+64), chunk sch; ds_write carries
    // the XOR swizzle chunk^((row>>1)&3); ds_read same involution.
    const int srow = tid >> 2;              // 0..63
    const int sch  = tid & 3;
    const size_t eBase = (size_t)e * EXP_CAP + rowBase;
    int ar0 = (srow < nRows) ? srow : 0;
    int ar1 = (srow + 64 < nRows) ? srow + 64 : 0;
    int tok0 = tokList[eBase + ar0];
    int tok1 = tokList[eBase + ar1];
    const short* a0 = embBf + (size_t)tok0 * ND + sch * 8;
    const short* a1 = embBf + (size_t)tok1 * ND + sch * 8;
    const short* b0 = wBf + ((size_t)e * NDM + nBase + srow) * ND + sch * 8;
    const short* b1 = wBf + ((size_t)e * NDM + nBase + srow + 64) * ND + sch * 8;
    const int wo0 = srow * 32 + (sch ^ ((srow >> 1) & 3)) * 8;
    const int wo1 = wo0 + 64 * 32;

    f32x4 acc[4][4];
#pragma unroll
    for (int i = 0; i < 4; ++i)
#pragma unroll
        for (int j = 0; j < 4; ++j)
            acc[i][j] = (f32x4){0.f, 0.f, 0.f, 0.f};

    bf16x8 ra0 = *(const bf16x8*)a0;
    bf16x8 ra1 = *(const bf16x8*)a1;
    bf16x8 rb0 = *(const bf16x8*)b0;
    bf16x8 rb1 = *(const bf16x8*)b1;

    const int pc = kg ^ ((fr >> 1) & 3);    // swizzled physical chunk (lane-const)
    for (int ks = 0; ks < ND / 32; ++ks) {  // 16 K-steps
        __syncthreads();
        *(bf16x8*)&SA[wo0] = ra0;
        *(bf16x8*)&SA[wo1] = ra1;
        *(bf16x8*)&SB[wo0] = rb0;
        *(bf16x8*)&SB[wo1] = rb1;
        __syncthreads();
        if (ks < ND / 32 - 1) {             // next-step loads retire under MFMA
            ra0 = *(const bf16x8*)(a0 + (ks + 1) * 32);
            ra1 = *(const bf16x8*)(a1 + (ks + 1) * 32);
            rb0 = *(const bf16x8*)(b0 + (ks + 1) * 32);
            rb1 = *(const bf16x8*)(b1 + (ks + 1) * 32);
        }
        bf16x8 af[4], bv[4];
#pragma unroll
        for (int i = 0; i < 4; ++i)
            af[i] = *(const bf16x8*)&SA[(wr * 64 + i * 16 + fr) * 32 + pc * 8];
#pragma unroll
        for (int j = 0; j < 4; ++j)
            bv[j] = *(const bf16x8*)&SB[(wc * 64 + j * 16 + fr) * 32 + pc * 8];
#pragma unroll
        for (int i = 0; i < 4; ++i)
#pragma unroll
            for (int j = 0; j < 4; ++j)
                acc[i][j] = __builtin_amdgcn_mfma_f32_16x16x32_bf16(af[i], bv[j], acc[i][j], 0, 0, 0);
    }

    // epilogue: compact bf16 write, page-local (128 rows x 256KB window)
#pragma unroll
    for (int i = 0; i < 4; ++i) {
#pragma unroll
        for (int r = 0; r < 4; ++r) {
            int row = wr * 64 + i * 16 + kg * 4 + r;
            if (row < nRows) {
                size_t crow = (size_t)(cBase + row) * NDM + nBase;
#pragma unroll
                for (int j = 0; j < 4; ++j)
                    projC[crow + wc * 64 + j * 16 + fr] = f2bf(acc[i][j][r]);
            }
        }
    }
}

// ---- kernel 4: ALL output rows, row-contiguous 4KB writes ----
__global__ void k_out(const int* __restrict__ pos, const int* __restrict__ sid,
                      const int* __restrict__ mod, const int* __restrict__ role,
                      const int* __restrict__ mask, const int* __restrict__ kidx,
                      const int* __restrict__ bOff,
                      const float* __restrict__ bp, const float* __restrict__ cls_c,
                      const float* __restrict__ pe, const float* __restrict__ ie,
                      const float* __restrict__ mrT,
                      const unsigned short* __restrict__ projC,
                      float* __restrict__ out) {
    int l1 = blockIdx.x;            // 0..2048
    int b  = blockIdx.y;            // 0..7
    int o  = threadIdx.x * 4;       // 256 threads x 4 floats = 1024
    float4 v;
    if (l1 == 0) {
        v = add4(add4(ld4(cls_c + o), ld4(pe + o)), ld4(ie + (size_t)NS * NDM + o));
    } else {
        int t = b * NL + l1 - 1;
        int p = pos[t], s = sid[t], mr = mod[t] * 3 + role[t];
        v = add4(ld4(pe + (size_t)p * NDM + o), ld4(ie + (size_t)s * NDM + o));
        v = add4(v, ld4(mrT + (size_t)mr * NDM + o));
        if (mask[t] != 0) {
            v = add4(v, ld4(bp + (size_t)s * NDM + o));
            int ki = kidx[t];
            if (ki >= 0 && ki < EXP_CAP) {
                const unsigned short* pr = projC + (size_t)(bOff[s] + ki) * NDM + o;
                v.x += bf2f(pr[0]); v.y += bf2f(pr[1]);
                v.z += bf2f(pr[2]); v.w += bf2f(pr[3]);
            }
        }
    }
    *(float4*)&out[((size_t)b * LP1 + l1) * NDM + o] = v;
}

extern "C" void kernel_launch(void* const* d_in, const int* in_sizes, int n_in,
                              void* d_out, int out_size, void* d_ws, size_t ws_size,
                              hipStream_t stream) {
    const float* emb  = (const float*)d_in[0];
    const int* pos    = (const int*)d_in[1];
    const int* sid    = (const int*)d_in[2];
    const int* mod    = (const int*)d_in[3];
    const int* role   = (const int*)d_in[4];
    const int* mask   = (const int*)d_in[5];   // np.bool_ pushed as int32
    const float* Wp   = (const float*)d_in[6];
    const float* bp   = (const float*)d_in[7];
    const float* cls  = (const float*)d_in[8];
    const float* pe   = (const float*)d_in[9];
    const float* ie   = (const float*)d_in[10];
    const float* me   = (const float*)d_in[11];
    const float* re   = (const float*)d_in[12];
    float* out = (float*)d_out;

    int* ws        = (int*)d_ws;
    int* cnt       = ws;                          // [0..31]
    int* meta      = ws + 32;                     // [32]
    int* bOff      = ws + 64;                     // [64..95]
    int4* tiles    = (int4*)(ws + 128);           // 160 * int4
    int* tokList   = ws + 1024;                   // 32*1024
    int* kidx      = ws + 33792;                  // 16384
    float* mrT     = (float*)(ws + 50176);        // 12*1024
    short* embBf   = (short*)((char*)d_ws + 262144);                         // 16.78 MB
    short* wBf     = (short*)((char*)d_ws + 262144 + (size_t)EMB_ELEMS * 2); // 33.55 MB
    unsigned short* projC = (unsigned short*)((char*)d_ws + 262144 +
                              (size_t)EMB_ELEMS * 2 + (size_t)W_ELEMS * 2);  // 33.55 MB
    // total ws: ~84.2 MB (r8-proven available)

    hipMemsetAsync(ws, 0, 64 * sizeof(int), stream);
    k_bucket<<<NTOK / 256, 256, 0, stream>>>(sid, mask, cnt, kidx, tokList, out);
    k_cvt<<<(EMB_ELEMS + W_ELEMS) / (256 * 32), 256, 0, stream>>>(
        emb, Wp, embBf, wBf, cnt, meta, bOff, tiles, me, re, mrT);

    dim3 gg(MAXTILES, NDM / 128);
    k_gemm<<<gg, 256, 0, stream>>>(embBf, wBf, tokList, tiles, meta, projC);

    dim3 go(LP1, NB);
    k_out<<<go, 256, 0, stream>>>(pos, sid, mod, role, mask, kidx, bOff,
                                  bp, cls, pe, ie, mrT, projC, out);
}